// Round 1
// baseline (3866.335 us; speedup 1.0000x reference)
//
#include <hip/hip_runtime.h>
#include <math.h>

#define DIM    512
#define KCB    8192
#define NROWS  32768

#define BM 128
#define BN 256
#define BK 32
#define TM 8
#define TN 8
#define NTHR 512

// ---------------------------------------------------------------------------
// numpy-style pairwise sum of squares over 512 contiguous floats.
// Mimics numpy pairwise_sum: 4 blocks of 128 (8 accumulators, sequential
// adds, fixed combine tree), then ((B0+B1)+(B2+B3)). Unfused mul/add
// (__fmul_rn/__fadd_rn) to match numpy's separate multiply+add rounding.
// ---------------------------------------------------------------------------
__device__ __forceinline__ float pairwise512_sq(const float* __restrict__ p) {
    float blk[4];
#pragma unroll
    for (int b = 0; b < 4; ++b) {
        const float* a = p + b * 128;
        float r[8];
#pragma unroll
        for (int j = 0; j < 8; ++j) r[j] = __fmul_rn(a[j], a[j]);
#pragma unroll
        for (int i = 8; i < 128; i += 8) {
#pragma unroll
            for (int j = 0; j < 8; ++j)
                r[j] = __fadd_rn(r[j], __fmul_rn(a[i + j], a[i + j]));
        }
        blk[b] = __fadd_rn(__fadd_rn(__fadd_rn(r[0], r[1]), __fadd_rn(r[2], r[3])),
                           __fadd_rn(__fadd_rn(r[4], r[5]), __fadd_rn(r[6], r[7])));
    }
    return __fadd_rn(__fadd_rn(blk[0], blk[1]), __fadd_rn(blk[2], blk[3]));
}

__global__ void ee_kernel(const float* __restrict__ E, float* __restrict__ ee) {
    int k = blockIdx.x * blockDim.x + threadIdx.x;
    if (k < KCB) ee[k] = pairwise512_sq(E + (size_t)k * DIM);
}

// ---------------------------------------------------------------------------
// Fused distance + argmin. Block: 128 rows x (all 8192 codes, in 256-wide
// tiles). 512 threads = 16 ty x 32 tx; thread tile TM=8 rows x TN=8 cols.
// d2 = fl(fl(zz - 2*dot) + ee)  (exact numpy formula order; 2*dot is exact
// so fmaf(-2,dot,zz) == fl(zz - fl(2*dot))). Strict-less argmin update in
// ascending-k order => first-occurrence (numpy argmin) tie-break.
// ---------------------------------------------------------------------------
__global__ __launch_bounds__(NTHR, 2)
void argmin_kernel(const float* __restrict__ Z, const float* __restrict__ E,
                   const float* __restrict__ ee, int* __restrict__ outIdx) {
    // staging LDS, later overlaid by the reduction buffers
    __shared__ __align__(16) char smem[(BK * (BM + 4) + BK * (BN + 4)) * 4];
    float (*As)[BM + 4] = (float (*)[BM + 4])smem;                       // [32][132]
    float (*Bs)[BN + 4] = (float (*)[BN + 4])(smem + BK * (BM + 4) * 4); // [32][260]
    __shared__ float zzs[BM];

    const int tid = threadIdx.x;
    const int tx = tid & 31;
    const int ty = tid >> 5;
    const int rowBase = blockIdx.x * BM;

    if (tid < BM) zzs[tid] = pairwise512_sq(Z + (size_t)(rowBase + tid) * DIM);
    __syncthreads();

    float zz[TM];
#pragma unroll
    for (int m = 0; m < TM; ++m) zz[m] = zzs[ty * TM + m];

    float bestV[TM];
    int bestI[TM];
#pragma unroll
    for (int m = 0; m < TM; ++m) { bestV[m] = __builtin_inff(); bestI[m] = 0; }

    for (int tile = 0; tile < KCB / BN; ++tile) {
        float acc[TM][TN];
#pragma unroll
        for (int m = 0; m < TM; ++m)
#pragma unroll
            for (int n = 0; n < TN; ++n) acc[m][n] = 0.0f;

        for (int kc = 0; kc < DIM; kc += BK) {
            __syncthreads();  // previous LDS contents fully consumed
            // stage Z tile (BM x BK), transposed into As[kk][row]
#pragma unroll
            for (int i = 0; i < (BM * BK / 4) / NTHR; ++i) {  // 2 iters
                int id4 = tid + i * NTHR;
                int r = id4 >> 3, c = id4 & 7;
                float4 v = *(const float4*)(Z + (size_t)(rowBase + r) * DIM + kc + c * 4);
                As[c * 4 + 0][r] = v.x;
                As[c * 4 + 1][r] = v.y;
                As[c * 4 + 2][r] = v.z;
                As[c * 4 + 3][r] = v.w;
            }
            // stage E tile (BN x BK), transposed into Bs[kk][col]
#pragma unroll
            for (int i = 0; i < (BN * BK / 4) / NTHR; ++i) {  // 4 iters
                int id4 = tid + i * NTHR;
                int r = id4 >> 3, c = id4 & 7;
                float4 v = *(const float4*)(E + (size_t)(tile * BN + r) * DIM + kc + c * 4);
                Bs[c * 4 + 0][r] = v.x;
                Bs[c * 4 + 1][r] = v.y;
                Bs[c * 4 + 2][r] = v.z;
                Bs[c * 4 + 3][r] = v.w;
            }
            __syncthreads();
#pragma unroll
            for (int kk = 0; kk < BK; ++kk) {
                float a[TM], b[TN];
                *(float4*)&a[0] = *(const float4*)&As[kk][ty * TM];
                *(float4*)&a[4] = *(const float4*)&As[kk][ty * TM + 4];
                *(float4*)&b[0] = *(const float4*)&Bs[kk][tx * TN];
                *(float4*)&b[4] = *(const float4*)&Bs[kk][tx * TN + 4];
#pragma unroll
                for (int m = 0; m < TM; ++m)
#pragma unroll
                    for (int n = 0; n < TN; ++n)
                        acc[m][n] = __builtin_fmaf(a[m], b[n], acc[m][n]);
            }
        }

        // argmin update for this 256-wide tile of codes
        float eev[TN];
        *(float4*)&eev[0] = *(const float4*)(ee + tile * BN + tx * TN);
        *(float4*)&eev[4] = *(const float4*)(ee + tile * BN + tx * TN + 4);
#pragma unroll
        for (int m = 0; m < TM; ++m) {
#pragma unroll
            for (int n = 0; n < TN; ++n) {
                float t = __builtin_fmaf(-2.0f, acc[m][n], zz[m]); // fl(zz - 2*dot)
                float d2 = __fadd_rn(t, eev[n]);                   // fl(t + ee)
                int kidx = tile * BN + tx * TN + n;
                if (d2 < bestV[m]) { bestV[m] = d2; bestI[m] = kidx; }
            }
        }
    }

    // cross-thread (tx) argmin reduction, overlaying the staging LDS
    __syncthreads();
    float (*redV)[33] = (float (*)[33])smem;                       // padded stride
    int   (*redI)[33] = (int (*)[33])(smem + BM * 33 * 4);
#pragma unroll
    for (int m = 0; m < TM; ++m) {
        redV[ty * TM + m][tx] = bestV[m];
        redI[ty * TM + m][tx] = bestI[m];
    }
    __syncthreads();
    if (tid < BM) {
        float bv = redV[tid][0];
        int bi = redI[tid][0];
        for (int j = 1; j < 32; ++j) {
            float v = redV[tid][j];
            int ii = redI[tid][j];
            if (v < bv || (v == bv && ii < bi)) { bv = v; bi = ii; }
        }
        outIdx[rowBase + tid] = bi;
    }
}

// ---------------------------------------------------------------------------
// Gather z_q, write z_q_st = fl(z_e + fl(z_q - z_e)) (exact ST-estimator
// rounding mimic), indices as float, and accumulate sum((z_q - z_e)^2) in f64.
// One wave per row.
// ---------------------------------------------------------------------------
__global__ void gather_kernel(const float* __restrict__ Z, const float* __restrict__ E,
                              const int* __restrict__ idx, float* __restrict__ outZ,
                              float* __restrict__ outIdxF, double* __restrict__ lossAcc) {
    int row = blockIdx.x;
    int t = threadIdx.x;  // 64 threads
    int k = idx[row];
    const float* zr = Z + (size_t)row * DIM;
    const float* er = E + (size_t)k * DIM;
    float* orow = outZ + (size_t)row * DIM;
    double s = 0.0;
#pragma unroll
    for (int i = 0; i < 2; ++i) {
        int off = (t + i * 64) * 4;
        float4 z4 = *(const float4*)(zr + off);
        float4 e4 = *(const float4*)(er + off);
        float dx = __fsub_rn(e4.x, z4.x);
        float dy = __fsub_rn(e4.y, z4.y);
        float dz = __fsub_rn(e4.z, z4.z);
        float dw = __fsub_rn(e4.w, z4.w);
        float4 st;
        st.x = __fadd_rn(z4.x, dx);
        st.y = __fadd_rn(z4.y, dy);
        st.z = __fadd_rn(z4.z, dz);
        st.w = __fadd_rn(z4.w, dw);
        *(float4*)(orow + off) = st;
        s += (double)dx * dx + (double)dy * dy + (double)dz * dz + (double)dw * dw;
    }
#pragma unroll
    for (int o = 32; o > 0; o >>= 1) s += __shfl_down(s, o, 64);
    if (t == 0) {
        atomicAdd(lossAcc, s);
        outIdxF[row] = (float)k;
    }
}

__global__ void finalize_kernel(const double* __restrict__ lossAcc,
                                float* __restrict__ outLoss) {
    double m = *lossAcc / (double)((size_t)NROWS * DIM);
    float mf = (float)m;
    float c = __fmul_rn(0.25f, mf);   // commitment = BETA * mean
    *outLoss = __fadd_rn(c, mf);      // vq_loss = commitment + embedding
}

// ---------------------------------------------------------------------------
// ws layout (bytes): [0,32768) float ee[8192]; [32768,163840) int idx[32768];
// [163840,163848) double loss accumulator.
// ---------------------------------------------------------------------------
extern "C" void kernel_launch(void* const* d_in, const int* in_sizes, int n_in,
                              void* d_out, int out_size, void* d_ws, size_t ws_size,
                              hipStream_t stream) {
    const float* Z = (const float*)d_in[0];   // z_e: 8*4096*512
    const float* E = (const float*)d_in[1];   // embeddings: 8192*512
    float* out = (float*)d_out;
    float* zq_out = out;                               // [0, 16777216)
    float* loss_out = out + (size_t)NROWS * DIM;       // [16777216]
    float* idxf_out = loss_out + 1;                    // [16777217, +32768)

    float* ee = (float*)d_ws;
    int* idx = (int*)((char*)d_ws + 32768);
    double* lossAcc = (double*)((char*)d_ws + 163840);

    hipMemsetAsync(lossAcc, 0, sizeof(double), stream);
    ee_kernel<<<KCB / 256, 256, 0, stream>>>(E, ee);
    argmin_kernel<<<NROWS / BM, NTHR, 0, stream>>>(Z, E, ee, idx);
    gather_kernel<<<NROWS, 64, 0, stream>>>(Z, E, idx, zq_out, idxf_out, lossAcc);
    finalize_kernel<<<1, 1, 0, stream>>>(lossAcc, loss_out);
}